// Round 7
// baseline (853.034 us; speedup 1.0000x reference)
//
#include <hip/hip_runtime.h>
#include <math.h>

#define NNODES 262144      // B*N
#define NEDGE  2097152     // NNODES*DEG
#define NB     256         // graphs
#define NPG    1024        // nodes per graph
#define EPG    8192        // edges per graph
#define DF     128         // feature dim

typedef unsigned short u16;
typedef unsigned int   u32;
typedef __attribute__((ext_vector_type(8))) short  short8;   // 8 x bf16 (4 VGPRs)
typedef __attribute__((ext_vector_type(4))) float  floatx4;  // MFMA accumulator

static constexpr int K1 = 820, K2 = 656, K3 = 525;

// ---- bf16 helpers (manual, RTNE) ----
__device__ inline float bflo(u32 u) { union { u32 i; float f; } c; c.i = u << 16;          return c.f; }
__device__ inline float bfhi(u32 u) { union { u32 i; float f; } c; c.i = u & 0xffff0000u;  return c.f; }
__device__ inline u32   f2bf(float f) {
  union { float f; u32 i; } c; c.f = f;
  const u32 r = c.i + 0x7fffu + ((c.i >> 16) & 1u);
  return r >> 16;
}
__device__ inline void acc8s(float* b, uint4 v, float f) {
  b[0] += bflo(v.x) * f; b[1] += bfhi(v.x) * f;
  b[2] += bflo(v.y) * f; b[3] += bfhi(v.y) * f;
  b[4] += bflo(v.z) * f; b[5] += bfhi(v.z) * f;
  b[6] += bflo(v.w) * f; b[7] += bfhi(v.w) * f;
}
__device__ inline uint4 pack8(const float* s, float k) {
  uint4 o;
  o.x = f2bf(s[0] * k) | (f2bf(s[1] * k) << 16);
  o.y = f2bf(s[2] * k) | (f2bf(s[3] * k) << 16);
  o.z = f2bf(s[4] * k) | (f2bf(s[5] * k) << 16);
  o.w = f2bf(s[6] * k) | (f2bf(s[7] * k) << 16);
  return o;
}

// ---------------- CSR build (1024 thr): counting sort by dst + deg/keep init ----
__global__ __launch_bounds__(1024) void build_csr_k(
    const int* __restrict__ ei, int* __restrict__ csr_src,
    int* __restrict__ row_off, int* __restrict__ row_cnt,
    float* __restrict__ degf, float* __restrict__ keep)
{
  __shared__ int cnt[NPG];
  __shared__ int roff[NPG];
  __shared__ int wsum[NPG];
  const int b = blockIdx.x, t = threadIdx.x;   // t in 0..1023
  const int* src = ei;
  const int* dst = ei + NEDGE;
  const int e0 = b * EPG;
  cnt[t] = 0;
  __syncthreads();
  for (int e = t; e < EPG; e += 1024) atomicAdd(&cnt[dst[e0 + e] & (NPG - 1)], 1);
  __syncthreads();
  const int v = cnt[t];
  wsum[t] = v;
  __syncthreads();
  for (int off = 1; off < NPG; off <<= 1) {
    const int u = (t >= off) ? wsum[t - off] : 0;
    __syncthreads();
    wsum[t] += u;
    __syncthreads();
  }
  const int base = wsum[t] - v;    // exclusive prefix
  roff[t] = base;
  const int n = b * NPG + t;
  row_off[n] = base;
  row_cnt[n] = v;
  degf[n]    = (float)v;           // layer-1 deg = full in-degree
  keep[n]    = 1.0f;
  __syncthreads();
  for (int e = t; e < EPG; e += 1024) {
    const int dl = dst[e0 + e] & (NPG - 1);
    const int pos = atomicAdd(&roff[dl], 1);
    csr_src[e0 + pos] = src[e0 + e];   // store GLOBAL src node id
  }
}

// ---------------- Embedding gather (f32 -> bf16, unscaled) + fac init -----------
__global__ __launch_bounds__(256) void gather_k(
    const int* __restrict__ x_ids, const float* __restrict__ emb,
    u16* __restrict__ x0, float* __restrict__ fac)
{
  const int gid = blockIdx.x * 256 + threadIdx.x;  // NNODES*16 threads
  const int n = gid >> 4, c = gid & 15;
  const int id = x_ids[n];
  const float4 v0 = *(const float4*)(emb + (size_t)id * DF + c * 8);
  const float4 v1 = *(const float4*)(emb + (size_t)id * DF + c * 8 + 4);
  uint4 pk;
  pk.x = f2bf(v0.x) | (f2bf(v0.y) << 16);
  pk.y = f2bf(v0.z) | (f2bf(v0.w) << 16);
  pk.z = f2bf(v1.x) | (f2bf(v1.y) << 16);
  pk.w = f2bf(v1.z) | (f2bf(v1.w) << 16);
  *(uint4*)(x0 + (size_t)n * DF + c * 8) = pk;
  if (c == 0) fac[n] = 1.0f;
}

// ---- Weight convert into SWIZZLED fragment order -------------------------------
// wF[l][f=ct*8+ks][lane][j] = wT[n=ct*16+(lane&15)][k=ks*32+(lane>>4)*8+j]
// where wT[n][k] = k<128 ? Wl[k][n] : Wr[k-128][n].  One wave per (l,f).
__global__ __launch_bounds__(64) void wcvt_k(
    const float* __restrict__ Wl1, const float* __restrict__ Wr1,
    const float* __restrict__ Wl2, const float* __restrict__ Wr2,
    const float* __restrict__ Wl3, const float* __restrict__ Wr3,
    u16* __restrict__ wF)
{
  const int f = blockIdx.x & 63, l = blockIdx.x >> 6;
  const int lane = threadIdx.x;
  const int ct = f >> 3, ks = f & 7;
  const int n = ct * 16 + (lane & 15);
  const int k0 = ks * 32 + (lane >> 4) * 8;
  const float* Wl = (l == 0) ? Wl1 : (l == 1) ? Wl2 : Wl3;
  const float* Wr = (l == 0) ? Wr1 : (l == 1) ? Wr2 : Wr3;
  u16 o[8];
#pragma unroll
  for (int j = 0; j < 8; ++j) {
    const int k = k0 + j;
    const float v = (k < 128) ? Wl[k * 128 + n] : Wr[(k - 128) * 128 + n];
    o[j] = (u16)f2bf(v);
  }
  uint4 pk;
  pk.x = (u32)o[0] | ((u32)o[1] << 16);
  pk.y = (u32)o[2] | ((u32)o[3] << 16);
  pk.z = (u32)o[4] | ((u32)o[5] << 16);
  pk.w = (u32)o[6] | ((u32)o[7] << 16);
  *(uint4*)(wF + (((size_t)l * 64 + f) * 64 + lane) * 8) = pk;
}

// ---- Fused layer: edge-parallel gather-agg (LDS) + MFMA GEMM + score -----------
// out = [agg | fac.x] @ [Wl;Wr] + bl, relu.  64 rows/block, 512 thr (8 waves).
// Phase A: thread=(node64, q4, es2), es-pairs combined via shfl_xor(1).
// Phase B: wave=(row-block4, col-half2); A k0..127 from LDS, k128..255 = fac.x.
__global__ __launch_bounds__(512) void fused_k(
    const u16* __restrict__ xprev, const float* __restrict__ fac,
    const float* __restrict__ deg,
    const int* __restrict__ csr_src, const int* __restrict__ row_off,
    const int* __restrict__ row_cnt,
    const u16* __restrict__ wF, const float* __restrict__ bl,
    const float* __restrict__ p,
    u16* __restrict__ xout, float* __restrict__ score)
{
  __shared__ u16 a_t[64 * 136];    // agg tile; reused as output tile after barrier
  __shared__ float sc[64 * 2];
  const int t = threadIdx.x;
  const int bi = blockIdx.x;                  // 4096 = 256 graphs x 16 tiles
  const int g = (bi & 7) + 8 * (bi >> 7);     // XCD swizzle
  const int tile = (bi >> 3) & 15;
  const int n0 = g * NPG + tile * 64;

  // ---- Phase A: agg into LDS ----
  {
    const int node = t >> 3, q = (t >> 1) & 3, es = t & 1;
    const int n = n0 + node;
    const int cnt = row_cnt[n];
    const int* ep = csr_src + g * EPG + row_off[n];
    const u16* xq = xprev + q * 32;
    float b[32];
#pragma unroll
    for (int j = 0; j < 32; ++j) b[j] = 0.0f;
    int e = es;
    for (; e + 2 < cnt; e += 4) {             // 2 edges/iter -> 8 uint4 in flight
      const int s0 = ep[e], s1 = ep[e + 2];
      const float f0 = fac[s0], f1 = fac[s1];
      const uint4* r0 = (const uint4*)(xq + (size_t)s0 * DF);
      const uint4* r1 = (const uint4*)(xq + (size_t)s1 * DF);
      const uint4 A0 = r0[0], A1 = r0[1], A2 = r0[2], A3 = r0[3];
      const uint4 B0 = r1[0], B1 = r1[1], B2 = r1[2], B3 = r1[3];
      acc8s(b + 0, A0, f0); acc8s(b + 8, A1, f0);
      acc8s(b + 16, A2, f0); acc8s(b + 24, A3, f0);
      acc8s(b + 0, B0, f1); acc8s(b + 8, B1, f1);
      acc8s(b + 16, B2, f1); acc8s(b + 24, B3, f1);
    }
    if (e < cnt) {
      const int s0 = ep[e];
      const float f0 = fac[s0];
      const uint4* r0 = (const uint4*)(xq + (size_t)s0 * DF);
      const uint4 A0 = r0[0], A1 = r0[1], A2 = r0[2], A3 = r0[3];
      acc8s(b + 0, A0, f0); acc8s(b + 8, A1, f0);
      acc8s(b + 16, A2, f0); acc8s(b + 24, A3, f0);
    }
#pragma unroll
    for (int j = 0; j < 32; ++j) b[j] += __shfl_xor(b[j], 1);
    if (es == 0) {
      const float inv = 1.0f / fmaxf(deg[n], 1.0f);
      uint4* ap = (uint4*)(a_t + node * 136 + q * 32);
      ap[0] = pack8(b + 0,  inv);
      ap[1] = pack8(b + 8,  inv);
      ap[2] = pack8(b + 16, inv);
      ap[3] = pack8(b + 24, inv);
    }
  }
  __syncthreads();

  // ---- Phase B: MFMA ----
  const int wv = t >> 6, lane = t & 63;
  const int rbk = wv >> 1, ch = wv & 1;
  const int lr = lane & 15, quad = lane >> 4;
  const int row = rbk * 16 + lr;
  const int grow = n0 + row;
  short8 af[8];
#pragma unroll
  for (int ks = 0; ks < 4; ++ks)
    af[ks] = *(const short8*)(a_t + row * 136 + ks * 32 + quad * 8);
  {
    const float fr = fac[grow];
#pragma unroll
    for (int ks = 0; ks < 4; ++ks) {
      const uint4 v = *(const uint4*)(xprev + (size_t)grow * DF + ks * 32 + quad * 8);
      union { uint4 u; short8 s; } c;
      c.u.x = f2bf(bflo(v.x) * fr) | (f2bf(bfhi(v.x) * fr) << 16);
      c.u.y = f2bf(bflo(v.y) * fr) | (f2bf(bfhi(v.y) * fr) << 16);
      c.u.z = f2bf(bflo(v.z) * fr) | (f2bf(bfhi(v.z) * fr) << 16);
      c.u.w = f2bf(bflo(v.w) * fr) | (f2bf(bfhi(v.w) * fr) << 16);
      af[4 + ks] = c.s;
    }
  }
  __syncthreads();   // all A-frags consumed from a_t -> reusable as output tile

  floatx4 acc[4];
#pragma unroll
  for (int ct = 0; ct < 4; ++ct) acc[ct] = (floatx4){0.f, 0.f, 0.f, 0.f};
#pragma unroll
  for (int ks = 0; ks < 8; ++ks) {
#pragma unroll
    for (int ct = 0; ct < 4; ++ct) {
      const int f = ((ch * 4 + ct) * 8 + ks);
      const short8 bf = *(const short8*)(wF + ((size_t)f * 64 + lane) * 8);
      acc[ct] = __builtin_amdgcn_mfma_f32_16x16x32_bf16(af[ks], bf, acc[ct], 0, 0, 0);
    }
  }
  // ---- epilogue: bias+relu, raw score halves, pack into a_t ----
  float si[4] = {0.f, 0.f, 0.f, 0.f};
#pragma unroll
  for (int ct = 0; ct < 4; ++ct) {
    const int nn = (ch * 4 + ct) * 16 + lr;
    const float bn = bl[nn], pn = p[nn];
#pragma unroll
    for (int r = 0; r < 4; ++r) {
      const float v = fmaxf(acc[ct][r] + bn, 0.0f);
      si[r] += v * pn;
      a_t[(rbk * 16 + quad * 4 + r) * 136 + nn] = (u16)f2bf(v);
    }
  }
#pragma unroll
  for (int r = 0; r < 4; ++r) {
    float s = si[r];
#pragma unroll
    for (int off = 1; off < 16; off <<= 1) s += __shfl_xor(s, off, 16);
    if (lr == 0) sc[(rbk * 16 + quad * 4 + r) * 2 + ch] = s;
  }
  __syncthreads();
  if (t < 64) score[n0 + t] = sc[t * 2] + sc[t * 2 + 1];
  {
    const int rw = t >> 3, sg = (t & 7) * 2;
#pragma unroll
    for (int i = 0; i < 2; ++i) {
      const uint4 v = *(const uint4*)(a_t + rw * 136 + (sg + i) * 8);
      *(uint4*)(xout + (size_t)(n0 + rw) * DF + (sg + i) * 8) = v;
    }
  }
}

// ---- Per-graph top-k rank (exact argsort semantics) + edge-parallel next-deg ---
__global__ __launch_bounds__(1024) void rank_k(
    const float* __restrict__ score, const float* __restrict__ p,
    const int* __restrict__ ei,
    float* __restrict__ keep, float* __restrict__ fac,
    float* __restrict__ degN, int K, int next)
{
  __shared__ float s_lds[NPG];
  __shared__ float kfl[NPG];
  __shared__ float deg_l[NPG];
  const int b = blockIdx.x, t = threadIdx.x;
  float ssq = 0.0f;
  for (int d = 0; d < DF; ++d) ssq += p[d] * p[d];
  const float inv_pn = 1.0f / sqrtf(ssq);
  const float NEG = -__builtin_huge_valf();
  {
    const int n = b * NPG + t;
    s_lds[t] = (keep[n] > 0.5f) ? score[n] : NEG;
    deg_l[t] = 0.0f;
  }
  __syncthreads();
  const float si = s_lds[t];
  int rk = 0;
  for (int j = 0; j < NPG; ++j) {
    const float sj = s_lds[j];
    rk += (sj > si) || ((sj == si) && (j < t));
  }
  const bool kp = rk < K;          // implies previously-active (inactive = -inf)
  const int n = b * NPG + t;
  keep[n] = kp ? 1.0f : 0.0f;
  kfl[t]  = kp ? 1.0f : 0.0f;
  fac[n]  = kp ? tanhf(si * inv_pn) : 0.0f;
  __syncthreads();
  if (next) {
    const int e0 = b * EPG;
    for (int e = t; e < EPG; e += 1024) {
      const int sl = ei[e0 + e] & (NPG - 1);
      const int dl = ei[NEDGE + e0 + e] & (NPG - 1);
      atomicAdd(&deg_l[dl], kfl[sl]);
    }
    __syncthreads();
    degN[n] = deg_l[t];
  }
}

// ---- Parallel masked readout: 8 blocks/graph (reads unscaled xn, applies fac) --
__global__ __launch_bounds__(256) void readout_k(
    const u16* __restrict__ xn, const float* __restrict__ fac,
    const float* __restrict__ keep, float* __restrict__ xlp)
{
  __shared__ float mxA[256], mxB[256], smA[256], smB[256];
  const int blk = blockIdx.x, b = blk >> 3, pr = blk & 7, t = threadIdx.x;
  const int d = t & 63, rq = t >> 6;
  const float NEG = -__builtin_huge_valf();
  float mx0 = NEG, mx1 = NEG, sm0 = 0.0f, sm1 = 0.0f;
  for (int j = 0; j < 32; ++j) {
    const int n = b * NPG + pr * 128 + rq + j * 4;
    const float kf = keep[n];
    const float f  = fac[n];
    const u32 u = *(const u32*)(xn + (size_t)n * DF + d * 2);
    const float v0 = bflo(u) * f, v1 = bfhi(u) * f;
    if (kf > 0.5f) {
      mx0 = fmaxf(mx0, v0); mx1 = fmaxf(mx1, v1);
      sm0 += v0; sm1 += v1;
    }
  }
  mxA[t] = mx0; mxB[t] = mx1; smA[t] = sm0; smB[t] = sm1;
  __syncthreads();
  if (t < 64) {
    float m0 = mxA[t], m1 = mxB[t], s0 = smA[t], s1 = smB[t];
#pragma unroll
    for (int qq = 1; qq < 4; ++qq) {
      m0 = fmaxf(m0, mxA[qq * 64 + t]); m1 = fmaxf(m1, mxB[qq * 64 + t]);
      s0 += smA[qq * 64 + t];           s1 += smB[qq * 64 + t];
    }
    float* o = xlp + (size_t)blk * 256;
    o[2 * t]           = m0;
    o[2 * t + 1]       = m1;
    o[128 + 2 * t]     = s0;
    o[128 + 2 * t + 1] = s1;
  }
}

// ---------------- Final MLP head, one block per graph ----------------
__global__ __launch_bounds__(256) void mlp_k(
    const float* __restrict__ xlp,
    const float* __restrict__ W1, const float* __restrict__ b1,
    const float* __restrict__ W2, const float* __restrict__ b2,
    const float* __restrict__ W3, const float* __restrict__ b3,
    float* __restrict__ out)
{
  __shared__ float h0[256];
  __shared__ float h1[128];
  __shared__ float h2[64];
  const int b = blockIdx.x, t = threadIdx.x;
  const float invK[3] = {1.0f / (float)K1, 1.0f / (float)K2, 1.0f / (float)K3};
  float v = 0.0f;
#pragma unroll
  for (int l = 0; l < 3; ++l) {
    const float* base = xlp + ((size_t)l * NB * 8 + (size_t)b * 8) * 256;
    if (t < 128) {
      float m = base[t];
#pragma unroll
      for (int pr = 1; pr < 8; ++pr) m = fmaxf(m, base[pr * 256 + t]);
      v += m;
    } else {
      float s = 0.0f;
#pragma unroll
      for (int pr = 0; pr < 8; ++pr) s += base[pr * 256 + t];
      v += s * invK[l];
    }
  }
  h0[t] = v;
  __syncthreads();
  if (t < 128) {
    float a = b1[t];
    for (int k = 0; k < 256; ++k) a += h0[k] * W1[k * 128 + t];
    h1[t] = fmaxf(a, 0.0f);
  }
  __syncthreads();
  if (t < 64) {
    float a = b2[t];
    for (int k = 0; k < 128; ++k) a += h1[k] * W2[k * 64 + t];
    h2[t] = fmaxf(a, 0.0f);
  }
  __syncthreads();
  if (t < 64) {
    float vv = h2[t] * W3[t];
#pragma unroll
    for (int off = 32; off > 0; off >>= 1) vv += __shfl_xor(vv, off, 64);
    if (t == 0) out[b] = 1.0f / (1.0f + expf(-(vv + b3[0])));
  }
}

extern "C" void kernel_launch(void* const* d_in, const int* in_sizes, int n_in,
                              void* d_out, int out_size, void* d_ws, size_t ws_size,
                              hipStream_t stream)
{
  const int*   x_ids = (const int*)d_in[0];
  const int*   ei    = (const int*)d_in[1];
  const float* emb   = (const float*)d_in[3];
  const float* Wl[3]  = {(const float*)d_in[4],  (const float*)d_in[8],  (const float*)d_in[12]};
  const float* blv[3] = {(const float*)d_in[5],  (const float*)d_in[9],  (const float*)d_in[13]};
  const float* Wr[3]  = {(const float*)d_in[6],  (const float*)d_in[10], (const float*)d_in[14]};
  const float* pv[3]  = {(const float*)d_in[7],  (const float*)d_in[11], (const float*)d_in[15]};
  const float* W1 = (const float*)d_in[16]; const float* b1 = (const float*)d_in[17];
  const float* W2 = (const float*)d_in[18]; const float* b2 = (const float*)d_in[19];
  const float* W3 = (const float*)d_in[20]; const float* b3 = (const float*)d_in[21];

  char* ws = (char*)d_ws;
  size_t off = 0;
  auto alloc = [&](size_t bytes) -> void* {
    void* ptr = ws + off; off += (bytes + 255) & ~(size_t)255; return ptr;
  };
  u16*   xA    = (u16*)  alloc((size_t)NNODES * DF * 2);   // feature ping
  u16*   xB    = (u16*)  alloc((size_t)NNODES * DF * 2);   // feature pong
  float* score = (float*)alloc((size_t)NNODES * 4);
  float* keep  = (float*)alloc((size_t)NNODES * 4);
  float* fac   = (float*)alloc((size_t)NNODES * 4);
  float* degf  = (float*)alloc((size_t)NNODES * 4);
  int*   csr   = (int*)  alloc((size_t)NEDGE * 4);
  int*   roff  = (int*)  alloc((size_t)NNODES * 4);
  int*   rcnt  = (int*)  alloc((size_t)NNODES * 4);
  u16*   wF    = (u16*)  alloc((size_t)3 * 64 * 64 * 8 * 2);
  float* xlp   = (float*)alloc((size_t)3 * NB * 8 * 256 * 4);
  (void)in_sizes; (void)n_in; (void)out_size;
  if (off > ws_size) return;   // graceful fail instead of OOB fault

  wcvt_k<<<192, 64, 0, stream>>>(Wl[0], Wr[0], Wl[1], Wr[1], Wl[2], Wr[2], wF);
  build_csr_k<<<NB, 1024, 0, stream>>>(ei, csr, roff, rcnt, degf, keep);
  gather_k<<<NNODES * 16 / 256, 256, 0, stream>>>(x_ids, emb, xA, fac);
  const int Ks[3] = {K1, K2, K3};
  u16* fin = xA; u16* fout = xB;
  for (int l = 0; l < 3; ++l) {
    fused_k<<<4096, 512, 0, stream>>>(fin, fac, degf, csr, roff, rcnt,
                                      wF + (size_t)l * 32768, blv[l], pv[l],
                                      fout, score);
    rank_k<<<NB, 1024, 0, stream>>>(score, pv[l], ei, keep, fac, degf,
                                    Ks[l], l < 2 ? 1 : 0);
    readout_k<<<NB * 8, 256, 0, stream>>>(fout, fac, keep,
                                          xlp + (size_t)l * NB * 8 * 256);
    u16* tmp = fin; fin = fout; fout = tmp;
  }
  mlp_k<<<NB, 256, 0, stream>>>(xlp, W1, b1, W2, b2, W3, b3, (float*)d_out);
}

// Round 8
// 793.246 us; speedup vs baseline: 1.0754x; 1.0754x over previous
//
#include <hip/hip_runtime.h>
#include <math.h>

#define NNODES 262144      // B*N
#define NEDGE  2097152     // NNODES*DEG
#define NB     256         // graphs
#define NPG    1024        // nodes per graph
#define EPG    8192        // edges per graph
#define DF     128         // feature dim

typedef unsigned short u16;
typedef unsigned int   u32;
typedef __attribute__((ext_vector_type(8))) short  short8;   // 8 x bf16 (4 VGPRs)
typedef __attribute__((ext_vector_type(4))) float  floatx4;  // MFMA accumulator

static constexpr int K1 = 820, K2 = 656, K3 = 525;

// ---- bf16 helpers (manual, RTNE) ----
__device__ inline float bflo(u32 u) { union { u32 i; float f; } c; c.i = u << 16;          return c.f; }
__device__ inline float bfhi(u32 u) { union { u32 i; float f; } c; c.i = u & 0xffff0000u;  return c.f; }
__device__ inline u32   f2bf(float f) {
  union { float f; u32 i; } c; c.f = f;
  const u32 r = c.i + 0x7fffu + ((c.i >> 16) & 1u);
  return r >> 16;
}
__device__ inline void acc8(float* b, uint4 v) {
  b[0] += bflo(v.x); b[1] += bfhi(v.x);
  b[2] += bflo(v.y); b[3] += bfhi(v.y);
  b[4] += bflo(v.z); b[5] += bfhi(v.z);
  b[6] += bflo(v.w); b[7] += bfhi(v.w);
}
__device__ inline uint4 pack8(const float* s, float k) {
  uint4 o;
  o.x = f2bf(s[0] * k) | (f2bf(s[1] * k) << 16);
  o.y = f2bf(s[2] * k) | (f2bf(s[3] * k) << 16);
  o.z = f2bf(s[4] * k) | (f2bf(s[5] * k) << 16);
  o.w = f2bf(s[6] * k) | (f2bf(s[7] * k) << 16);
  return o;
}

// ---------------- CSR build (1024 thr): counting sort by dst + deg/keep init ----
__global__ __launch_bounds__(1024) void build_csr_k(
    const int* __restrict__ ei, int* __restrict__ csr_src,
    int* __restrict__ row_off, int* __restrict__ row_cnt,
    float* __restrict__ degf, float* __restrict__ keep)
{
  __shared__ int cnt[NPG];
  __shared__ int roff[NPG];
  __shared__ int wsum[NPG];
  const int b = blockIdx.x, t = threadIdx.x;   // t in 0..1023
  const int* src = ei;
  const int* dst = ei + NEDGE;
  const int e0 = b * EPG;
  cnt[t] = 0;
  __syncthreads();
  for (int e = t; e < EPG; e += 1024) atomicAdd(&cnt[dst[e0 + e] & (NPG - 1)], 1);
  __syncthreads();
  const int v = cnt[t];
  wsum[t] = v;
  __syncthreads();
  for (int off = 1; off < NPG; off <<= 1) {
    const int u = (t >= off) ? wsum[t - off] : 0;
    __syncthreads();
    wsum[t] += u;
    __syncthreads();
  }
  const int base = wsum[t] - v;    // exclusive prefix
  roff[t] = base;
  const int n = b * NPG + t;
  row_off[n] = base;
  row_cnt[n] = v;
  degf[n]    = (float)v;           // layer-1 deg = full in-degree
  keep[n]    = 1.0f;
  __syncthreads();
  for (int e = t; e < EPG; e += 1024) {
    const int dl = dst[e0 + e] & (NPG - 1);
    const int pos = atomicAdd(&roff[dl], 1);
    csr_src[e0 + pos] = src[e0 + e];   // store GLOBAL src node id
  }
}

// ---------------- Embedding gather (f32 -> bf16, unscaled) + fac init -----------
__global__ __launch_bounds__(256) void gather_k(
    const int* __restrict__ x_ids, const float* __restrict__ emb,
    u16* __restrict__ x0, float* __restrict__ fac)
{
  const int gid = blockIdx.x * 256 + threadIdx.x;  // NNODES*16 threads
  const int n = gid >> 4, c = gid & 15;
  const int id = x_ids[n];
  const float4 v0 = *(const float4*)(emb + (size_t)id * DF + c * 8);
  const float4 v1 = *(const float4*)(emb + (size_t)id * DF + c * 8 + 4);
  uint4 pk;
  pk.x = f2bf(v0.x) | (f2bf(v0.y) << 16);
  pk.y = f2bf(v0.z) | (f2bf(v0.w) << 16);
  pk.z = f2bf(v1.x) | (f2bf(v1.y) << 16);
  pk.w = f2bf(v1.z) | (f2bf(v1.w) << 16);
  *(uint4*)(x0 + (size_t)n * DF + c * 8) = pk;
  if (c == 0) fac[n] = 1.0f;
}

// ---- Weight convert into SWIZZLED fragment order -------------------------------
// wF[l][f=ct*8+ks][lane][j] = wT[n=ct*16+(lane&15)][k=ks*32+(lane>>4)*8+j]
// where wT[n][k] = k<128 ? Wl[k][n] : Wr[k-128][n].  One wave per (l,f).
__global__ __launch_bounds__(64) void wcvt_k(
    const float* __restrict__ Wl1, const float* __restrict__ Wr1,
    const float* __restrict__ Wl2, const float* __restrict__ Wr2,
    const float* __restrict__ Wl3, const float* __restrict__ Wr3,
    u16* __restrict__ wF)
{
  const int f = blockIdx.x & 63, l = blockIdx.x >> 6;
  const int lane = threadIdx.x;
  const int ct = f >> 3, ks = f & 7;
  const int n = ct * 16 + (lane & 15);
  const int k0 = ks * 32 + (lane >> 4) * 8;
  const float* Wl = (l == 0) ? Wl1 : (l == 1) ? Wl2 : Wl3;
  const float* Wr = (l == 0) ? Wr1 : (l == 1) ? Wr2 : Wr3;
  u16 o[8];
#pragma unroll
  for (int j = 0; j < 8; ++j) {
    const int k = k0 + j;
    const float v = (k < 128) ? Wl[k * 128 + n] : Wr[(k - 128) * 128 + n];
    o[j] = (u16)f2bf(v);
  }
  uint4 pk;
  pk.x = (u32)o[0] | ((u32)o[1] << 16);
  pk.y = (u32)o[2] | ((u32)o[3] << 16);
  pk.z = (u32)o[4] | ((u32)o[5] << 16);
  pk.w = (u32)o[6] | ((u32)o[7] << 16);
  *(uint4*)(wF + (((size_t)l * 64 + f) * 64 + lane) * 8) = pk;
}

// ---- Aggregation v3: LDS-staged gather at full width ---------------------------
// block = (graph, 32-feat quarter), 1024 thr (1 thread : 1 node).
// Stage graph's quarter scaled+bf16 into 64 KB LDS (16B-group XOR swizzle),
// then each thread CSR-walks its node with ds_read_b128. agg = sum/max(deg,1).
__global__ __launch_bounds__(1024) void agg_k(
    const u16* __restrict__ xprev, const float* __restrict__ fac,
    const float* __restrict__ deg,
    const int* __restrict__ csr_src, const int* __restrict__ row_off,
    const int* __restrict__ row_cnt,
    u16* __restrict__ aggb)
{
  __shared__ u32 xl[16384];          // 64 KB: 1024 rows x 16 dwords (32 bf16)
  const int t = threadIdx.x;
  const int bi = blockIdx.x;         // 1024 = 256 graphs x 4 quarters
  const int g  = (bi & 7) + 8 * (bi >> 5);     // XCD swizzle
  const int qt = (bi >> 3) & 3;
  const int n  = g * NPG + t;
  // ---- stage (scaled, swizzled) ----
  {
    const float fr = fac[n];
    const uint4* src = (const uint4*)(xprev + (size_t)n * DF + qt * 32);
    u32* dst = xl + t * 16;
    const int sw = (t & 3) << 2;
#pragma unroll
    for (int j = 0; j < 4; ++j) {
      const uint4 v = src[j];
      uint4 o;
      o.x = f2bf(bflo(v.x) * fr) | (f2bf(bfhi(v.x) * fr) << 16);
      o.y = f2bf(bflo(v.y) * fr) | (f2bf(bfhi(v.y) * fr) << 16);
      o.z = f2bf(bflo(v.z) * fr) | (f2bf(bfhi(v.z) * fr) << 16);
      o.w = f2bf(bflo(v.w) * fr) | (f2bf(bfhi(v.w) * fr) << 16);
      *(uint4*)(dst + ((j << 2) ^ sw)) = o;
    }
  }
  __syncthreads();
  // ---- gather-sum from LDS ----
  const int cnt = row_cnt[n];
  const int* ep = csr_src + g * EPG + row_off[n];
  float b[32];
#pragma unroll
  for (int j = 0; j < 32; ++j) b[j] = 0.0f;
  int e = 0;
  for (; e + 2 <= cnt; e += 2) {
    const int s0 = ep[e] & (NPG - 1), s1 = ep[e + 1] & (NPG - 1);
    const u32* r0 = xl + s0 * 16; const int w0 = (s0 & 3) << 2;
    const u32* r1 = xl + s1 * 16; const int w1 = (s1 & 3) << 2;
    const uint4 A0 = *(const uint4*)(r0 + (0  ^ w0));
    const uint4 A1 = *(const uint4*)(r0 + (4  ^ w0));
    const uint4 A2 = *(const uint4*)(r0 + (8  ^ w0));
    const uint4 A3 = *(const uint4*)(r0 + (12 ^ w0));
    const uint4 B0 = *(const uint4*)(r1 + (0  ^ w1));
    const uint4 B1 = *(const uint4*)(r1 + (4  ^ w1));
    const uint4 B2 = *(const uint4*)(r1 + (8  ^ w1));
    const uint4 B3 = *(const uint4*)(r1 + (12 ^ w1));
    acc8(b + 0, A0); acc8(b + 8, A1); acc8(b + 16, A2); acc8(b + 24, A3);
    acc8(b + 0, B0); acc8(b + 8, B1); acc8(b + 16, B2); acc8(b + 24, B3);
  }
  if (e < cnt) {
    const int s0 = ep[e] & (NPG - 1);
    const u32* r0 = xl + s0 * 16; const int w0 = (s0 & 3) << 2;
    const uint4 A0 = *(const uint4*)(r0 + (0  ^ w0));
    const uint4 A1 = *(const uint4*)(r0 + (4  ^ w0));
    const uint4 A2 = *(const uint4*)(r0 + (8  ^ w0));
    const uint4 A3 = *(const uint4*)(r0 + (12 ^ w0));
    acc8(b + 0, A0); acc8(b + 8, A1); acc8(b + 16, A2); acc8(b + 24, A3);
  }
  const float inv = 1.0f / fmaxf(deg[n], 1.0f);
  uint4* op = (uint4*)(aggb + (size_t)n * DF + qt * 32);
  op[0] = pack8(b + 0,  inv);
  op[1] = pack8(b + 8,  inv);
  op[2] = pack8(b + 16, inv);
  op[3] = pack8(b + 24, inv);
}

// ---- MFMA GEMM v3: B-frags in registers, in-place output -----------------------
// out = [agg | fac.x] @ W + bl, relu, raw score.  block = 512 thr = 8 waves
// (4 row-groups x 2 col-halves), 256 rows/block, 4 tiles of 16 rows per wave.
// G holds agg on entry, xn on exit (tile rows read pre-barrier, stored post).
__global__ __launch_bounds__(512) void gemm_k(
    u16* __restrict__ G, const u16* __restrict__ F,
    const float* __restrict__ fac,
    const u16* __restrict__ wF, const float* __restrict__ bl,
    const float* __restrict__ p, float* __restrict__ score)
{
  __shared__ u16 strip[4][16 * 136];   // per-rg output pack (17.4 KB)
  __shared__ float sc[256][2];
  const int t = threadIdx.x;
  const int bi = blockIdx.x;           // 1024 = 256 graphs x 4
  const int g   = (bi & 7) + 8 * (bi >> 5);
  const int tpg = (bi >> 3) & 3;
  const int n0  = g * NPG + tpg * 256;
  const int wv = t >> 6, lane = t & 63;
  const int rg = wv >> 1, ch = wv & 1;
  const int lr = lane & 15, quad = lane >> 4;

  // B-fragments for this wave's col-half: held in registers for the whole kernel
  short8 bf[4][8];
#pragma unroll
  for (int ct = 0; ct < 4; ++ct)
#pragma unroll
    for (int ks = 0; ks < 8; ++ks) {
      const int f = (ch * 4 + ct) * 8 + ks;
      bf[ct][ks] = *(const short8*)(wF + ((size_t)f * 64 + lane) * 8);
    }
  float bn[4], pn[4];
#pragma unroll
  for (int ct = 0; ct < 4; ++ct) {
    const int nn = (ch * 4 + ct) * 16 + lr;
    bn[ct] = bl[nn]; pn[ct] = p[nn];
  }

#pragma unroll 1
  for (int tl = 0; tl < 4; ++tl) {
    const int rbase = n0 + rg * 64 + tl * 16;
    const int row = rbase + lr;
    short8 af[8];
#pragma unroll
    for (int ks = 0; ks < 4; ++ks)
      af[ks] = *(const short8*)(G + (size_t)row * DF + ks * 32 + quad * 8);
    {
      const float fr = fac[row];
#pragma unroll
      for (int ks = 0; ks < 4; ++ks) {
        const uint4 v = *(const uint4*)(F + (size_t)row * DF + ks * 32 + quad * 8);
        union { uint4 u; short8 s; } c;
        c.u.x = f2bf(bflo(v.x) * fr) | (f2bf(bfhi(v.x) * fr) << 16);
        c.u.y = f2bf(bflo(v.y) * fr) | (f2bf(bfhi(v.y) * fr) << 16);
        c.u.z = f2bf(bflo(v.z) * fr) | (f2bf(bfhi(v.z) * fr) << 16);
        c.u.w = f2bf(bflo(v.w) * fr) | (f2bf(bfhi(v.w) * fr) << 16);
        af[4 + ks] = c.s;
      }
    }
    floatx4 acc[4];
#pragma unroll
    for (int ct = 0; ct < 4; ++ct) acc[ct] = (floatx4){0.f, 0.f, 0.f, 0.f};
#pragma unroll
    for (int ks = 0; ks < 8; ++ks)
#pragma unroll
      for (int ct = 0; ct < 4; ++ct)
        acc[ct] = __builtin_amdgcn_mfma_f32_16x16x32_bf16(af[ks], bf[ct][ks], acc[ct], 0, 0, 0);
    // epilogue: bias+relu, score partials, pack into rg strip
    float si[4] = {0.f, 0.f, 0.f, 0.f};
#pragma unroll
    for (int ct = 0; ct < 4; ++ct) {
#pragma unroll
      for (int r = 0; r < 4; ++r) {
        const float v = fmaxf(acc[ct][r] + bn[ct], 0.0f);
        si[r] += v * pn[ct];
        strip[rg][(quad * 4 + r) * 136 + (ch * 4 + ct) * 16 + lr] = (u16)f2bf(v);
      }
    }
#pragma unroll
    for (int r = 0; r < 4; ++r) {
      float s = si[r];
#pragma unroll
      for (int off = 1; off < 16; off <<= 1) s += __shfl_xor(s, off, 16);
      if (lr == 0) sc[rg * 64 + tl * 16 + quad * 4 + r][ch] = s;
    }
    __syncthreads();   // strip complete (both ch waves)
    {
      const int pl = ch * 64 + lane;      // 128 lanes per rg pair
      const int rr = pl >> 3, seg = pl & 7;
      const uint4 v = *(const uint4*)(&strip[rg][rr * 136 + seg * 8]);
      *(uint4*)(G + (size_t)(rbase + rr) * DF + seg * 8) = v;
    }
    __syncthreads();   // strip reusable
  }
  if (t < 256) score[n0 + t] = sc[t][0] + sc[t][1];
}

// ---- Per-graph top-k rank (exact argsort semantics) + edge-parallel next-deg ---
__global__ __launch_bounds__(1024) void rank_k(
    const float* __restrict__ score, const float* __restrict__ p,
    const int* __restrict__ ei,
    float* __restrict__ keep, float* __restrict__ fac,
    float* __restrict__ degN, int K, int next)
{
  __shared__ float s_lds[NPG];
  __shared__ float kfl[NPG];
  __shared__ float deg_l[NPG];
  const int b = blockIdx.x, t = threadIdx.x;
  float ssq = 0.0f;
  for (int d = 0; d < DF; ++d) ssq += p[d] * p[d];
  const float inv_pn = 1.0f / sqrtf(ssq);
  const float NEG = -__builtin_huge_valf();
  {
    const int n = b * NPG + t;
    s_lds[t] = (keep[n] > 0.5f) ? score[n] : NEG;
    deg_l[t] = 0.0f;
  }
  __syncthreads();
  const float si = s_lds[t];
  int rk = 0;
  for (int j = 0; j < NPG; ++j) {
    const float sj = s_lds[j];
    rk += (sj > si) || ((sj == si) && (j < t));
  }
  const bool kp = rk < K;          // implies previously-active (inactive = -inf)
  const int n = b * NPG + t;
  keep[n] = kp ? 1.0f : 0.0f;
  kfl[t]  = kp ? 1.0f : 0.0f;
  fac[n]  = kp ? tanhf(si * inv_pn) : 0.0f;
  __syncthreads();
  if (next) {
    const int e0 = b * EPG;
    for (int e = t; e < EPG; e += 1024) {
      const int sl = ei[e0 + e] & (NPG - 1);
      const int dl = ei[NEDGE + e0 + e] & (NPG - 1);
      atomicAdd(&deg_l[dl], kfl[sl]);
    }
    __syncthreads();
    degN[n] = deg_l[t];
  }
}

// ---- Parallel masked readout: 8 blocks/graph (reads unscaled xn, applies fac) --
__global__ __launch_bounds__(256) void readout_k(
    const u16* __restrict__ xn, const float* __restrict__ fac,
    const float* __restrict__ keep, float* __restrict__ xlp)
{
  __shared__ float mxA[256], mxB[256], smA[256], smB[256];
  const int blk = blockIdx.x, b = blk >> 3, pr = blk & 7, t = threadIdx.x;
  const int d = t & 63, rq = t >> 6;
  const float NEG = -__builtin_huge_valf();
  float mx0 = NEG, mx1 = NEG, sm0 = 0.0f, sm1 = 0.0f;
  for (int j = 0; j < 32; ++j) {
    const int n = b * NPG + pr * 128 + rq + j * 4;
    const float kf = keep[n];
    const float f  = fac[n];
    const u32 u = *(const u32*)(xn + (size_t)n * DF + d * 2);
    const float v0 = bflo(u) * f, v1 = bfhi(u) * f;
    if (kf > 0.5f) {
      mx0 = fmaxf(mx0, v0); mx1 = fmaxf(mx1, v1);
      sm0 += v0; sm1 += v1;
    }
  }
  mxA[t] = mx0; mxB[t] = mx1; smA[t] = sm0; smB[t] = sm1;
  __syncthreads();
  if (t < 64) {
    float m0 = mxA[t], m1 = mxB[t], s0 = smA[t], s1 = smB[t];
#pragma unroll
    for (int qq = 1; qq < 4; ++qq) {
      m0 = fmaxf(m0, mxA[qq * 64 + t]); m1 = fmaxf(m1, mxB[qq * 64 + t]);
      s0 += smA[qq * 64 + t];           s1 += smB[qq * 64 + t];
    }
    float* o = xlp + (size_t)blk * 256;
    o[2 * t]           = m0;
    o[2 * t + 1]       = m1;
    o[128 + 2 * t]     = s0;
    o[128 + 2 * t + 1] = s1;
  }
}

// ---------------- Final MLP head, one block per graph ----------------
__global__ __launch_bounds__(256) void mlp_k(
    const float* __restrict__ xlp,
    const float* __restrict__ W1, const float* __restrict__ b1,
    const float* __restrict__ W2, const float* __restrict__ b2,
    const float* __restrict__ W3, const float* __restrict__ b3,
    float* __restrict__ out)
{
  __shared__ float h0[256];
  __shared__ float h1[128];
  __shared__ float h2[64];
  const int b = blockIdx.x, t = threadIdx.x;
  const float invK[3] = {1.0f / (float)K1, 1.0f / (float)K2, 1.0f / (float)K3};
  float v = 0.0f;
#pragma unroll
  for (int l = 0; l < 3; ++l) {
    const float* base = xlp + ((size_t)l * NB * 8 + (size_t)b * 8) * 256;
    if (t < 128) {
      float m = base[t];
#pragma unroll
      for (int pr = 1; pr < 8; ++pr) m = fmaxf(m, base[pr * 256 + t]);
      v += m;
    } else {
      float s = 0.0f;
#pragma unroll
      for (int pr = 0; pr < 8; ++pr) s += base[pr * 256 + t];
      v += s * invK[l];
    }
  }
  h0[t] = v;
  __syncthreads();
  if (t < 128) {
    float a = b1[t];
    for (int k = 0; k < 256; ++k) a += h0[k] * W1[k * 128 + t];
    h1[t] = fmaxf(a, 0.0f);
  }
  __syncthreads();
  if (t < 64) {
    float a = b2[t];
    for (int k = 0; k < 128; ++k) a += h1[k] * W2[k * 64 + t];
    h2[t] = fmaxf(a, 0.0f);
  }
  __syncthreads();
  if (t < 64) {
    float vv = h2[t] * W3[t];
#pragma unroll
    for (int off = 32; off > 0; off >>= 1) vv += __shfl_xor(vv, off, 64);
    if (t == 0) out[b] = 1.0f / (1.0f + expf(-(vv + b3[0])));
  }
}

extern "C" void kernel_launch(void* const* d_in, const int* in_sizes, int n_in,
                              void* d_out, int out_size, void* d_ws, size_t ws_size,
                              hipStream_t stream)
{
  const int*   x_ids = (const int*)d_in[0];
  const int*   ei    = (const int*)d_in[1];
  const float* emb   = (const float*)d_in[3];
  const float* Wl[3]  = {(const float*)d_in[4],  (const float*)d_in[8],  (const float*)d_in[12]};
  const float* blv[3] = {(const float*)d_in[5],  (const float*)d_in[9],  (const float*)d_in[13]};
  const float* Wr[3]  = {(const float*)d_in[6],  (const float*)d_in[10], (const float*)d_in[14]};
  const float* pv[3]  = {(const float*)d_in[7],  (const float*)d_in[11], (const float*)d_in[15]};
  const float* W1 = (const float*)d_in[16]; const float* b1 = (const float*)d_in[17];
  const float* W2 = (const float*)d_in[18]; const float* b2 = (const float*)d_in[19];
  const float* W3 = (const float*)d_in[20]; const float* b3 = (const float*)d_in[21];

  char* ws = (char*)d_ws;
  size_t off = 0;
  auto alloc = [&](size_t bytes) -> void* {
    void* ptr = ws + off; off += (bytes + 255) & ~(size_t)255; return ptr;
  };
  u16*   xA    = (u16*)  alloc((size_t)NNODES * DF * 2);   // features / agg ping
  u16*   xB    = (u16*)  alloc((size_t)NNODES * DF * 2);   // features / agg pong
  float* score = (float*)alloc((size_t)NNODES * 4);
  float* keep  = (float*)alloc((size_t)NNODES * 4);
  float* fac   = (float*)alloc((size_t)NNODES * 4);
  float* degf  = (float*)alloc((size_t)NNODES * 4);
  int*   csr   = (int*)  alloc((size_t)NEDGE * 4);
  int*   roff  = (int*)  alloc((size_t)NNODES * 4);
  int*   rcnt  = (int*)  alloc((size_t)NNODES * 4);
  u16*   wF    = (u16*)  alloc((size_t)3 * 64 * 64 * 8 * 2);
  float* xlp   = (float*)alloc((size_t)3 * NB * 8 * 256 * 4);
  (void)in_sizes; (void)n_in; (void)out_size;
  if (off > ws_size) return;   // graceful fail instead of OOB fault

  wcvt_k<<<192, 64, 0, stream>>>(Wl[0], Wr[0], Wl[1], Wr[1], Wl[2], Wr[2], wF);
  build_csr_k<<<NB, 1024, 0, stream>>>(ei, csr, roff, rcnt, degf, keep);
  gather_k<<<NNODES * 16 / 256, 256, 0, stream>>>(x_ids, emb, xA, fac);
  const int Ks[3] = {K1, K2, K3};
  u16* F = xA;   // current features (unscaled)
  u16* G = xB;   // agg -> xn (in-place)
  for (int l = 0; l < 3; ++l) {
    agg_k<<<1024, 1024, 0, stream>>>(F, fac, degf, csr, roff, rcnt, G);
    gemm_k<<<1024, 512, 0, stream>>>(G, F, fac, wF + (size_t)l * 32768,
                                     blv[l], pv[l], score);
    rank_k<<<NB, 1024, 0, stream>>>(score, pv[l], ei, keep, fac, degf,
                                    Ks[l], l < 2 ? 1 : 0);
    readout_k<<<NB * 8, 256, 0, stream>>>(G, fac, keep,
                                          xlp + (size_t)l * NB * 8 * 256);
    u16* tmp = F; F = G; G = tmp;   // xn becomes next layer's features
  }
  mlp_k<<<NB, 256, 0, stream>>>(xlp, W1, b1, W2, b2, W3, b3, (float*)d_out);
}